// Round 1
// baseline (1016.425 us; speedup 1.0000x reference)
//
#include <hip/hip_runtime.h>
#include <math.h>

// MADDPG actor inference: obs-build + 39->64->64->5 MLP, B=1M items.
// Layout: one thread per batch item. Weights are wave-uniform -> scalar
// loads (s_load) + v_fmac with SGPR operand. Activations stream through a
// column-private LDS buffer (no dynamic VGPR indexing, no barriers).

#define NROW 20
#define NF   7
#define ITEM_F (NROW * NF)   // 140 floats per item
#define BLOCK 128

__global__ __launch_bounds__(BLOCK) void maddpg_kernel(
    const float* __restrict__ x,
    const float* __restrict__ W1, const float* __restrict__ b1,
    const float* __restrict__ W2, const float* __restrict__ b2,
    const float* __restrict__ W3, const float* __restrict__ b3,
    const int*   __restrict__ idx,
    float2*      __restrict__ out,
    int nitems)
{
    // 64 rows x BLOCK cols; each thread owns column tid.
    // rows 0..38: obs, then reused for h1 (0..63), then h2 (0..63).
    __shared__ float buf[64 * BLOCK];

    const int tid = threadIdx.x;
    const long b  = (long)blockIdx.x * BLOCK + tid;
    if (b >= nitems) return;

    const float* xb = x + b * (long)ITEM_F;

    // ---------------- build observation (39 floats) into LDS ----------------
    float4 s0 = *(const float4*)(xb);   // x[b,0,0..3]
    float  s4 = xb[4];                  // x[b,0,4]
    const float px = s0.x, py = s0.y;
    buf[0*BLOCK + tid] = s0.x;
    buf[1*BLOCK + tid] = s0.y;
    buf[2*BLOCK + tid] = s0.z;
    buf[3*BLOCK + tid] = s0.w;
    buf[4*BLOCK + tid] = s4;

    #pragma unroll
    for (int t = 0; t < 3; t++) {
        const float* xr = xb + idx[t] * NF;
        float2 p01 = *(const float2*)(xr);       // cols 0,1
        float2 p56 = *(const float2*)(xr + 5);   // cols 5,6
        buf[(5 + 3*t + 0)*BLOCK + tid] = p56.x + p01.x - px;
        buf[(5 + 3*t + 1)*BLOCK + tid] = p56.y + p01.y - py;
        buf[(5 + 3*t + 2)*BLOCK + tid] = 0.0f;
    }

    #pragma unroll
    for (int t = 0; t < 5; t++) {
        const float* xr = xb + (idx[3 + t] + NROW/2) * NF;
        float4 q  = *(const float4*)(xr);        // cols 0..3
        float  q4 = xr[4];                       // col 4
        float dx = q.x - px, dy = q.y - py;
        bool  m  = sqrtf(dx*dx + dy*dy) < 0.15f;
        buf[(14 + 5*t + 0)*BLOCK + tid] = m ? dx  : 0.0f;
        buf[(14 + 5*t + 1)*BLOCK + tid] = m ? dy  : 0.0f;
        buf[(14 + 5*t + 2)*BLOCK + tid] = m ? q.z : 0.0f;
        buf[(14 + 5*t + 3)*BLOCK + tid] = m ? q.w : 0.0f;
        buf[(14 + 5*t + 4)*BLOCK + tid] = m ? q4  : 0.0f;
    }

    // ---------------- layer 1: 39 -> 64 ----------------
    float h[64];
    #pragma unroll
    for (int k = 0; k < 64; k++) h[k] = b1[k];

    #pragma unroll 1
    for (int i = 0; i < 39; i++) {
        float o = buf[i*BLOCK + tid];            // ds_read, column-private
        const float* w = W1 + i * 64;            // wave-uniform -> s_load
        #pragma unroll
        for (int k = 0; k < 64; k++) h[k] = fmaf(o, w[k], h[k]);
    }
    #pragma unroll
    for (int k = 0; k < 64; k++) buf[k*BLOCK + tid] = fmaxf(h[k], 0.0f);

    // ---------------- layer 2: 64 -> 64 ----------------
    #pragma unroll
    for (int k = 0; k < 64; k++) h[k] = b2[k];

    #pragma unroll 1
    for (int i = 0; i < 64; i++) {
        float o = buf[i*BLOCK + tid];
        const float* w = W2 + i * 64;
        #pragma unroll
        for (int k = 0; k < 64; k++) h[k] = fmaf(o, w[k], h[k]);
    }
    #pragma unroll
    for (int k = 0; k < 64; k++) buf[k*BLOCK + tid] = fmaxf(h[k], 0.0f);

    // ---------------- layer 3: only r1,r2,r3,r4 are needed ----------------
    float r1 = b3[1], r2 = b3[2], r3 = b3[3], r4 = b3[4];
    #pragma unroll 1
    for (int i = 0; i < 64; i++) {
        float o = buf[i*BLOCK + tid];
        const float* w = W3 + i * 5;
        r1 = fmaf(o, w[1], r1);
        r2 = fmaf(o, w[2], r2);
        r3 = fmaf(o, w[3], r3);
        r4 = fmaf(o, w[4], r4);
    }

    float v0 = (r1 - r2) * 0.1f;
    float v1 = (r3 - r4) * 0.1f;
    if (fabsf(v0) > 1.0f) v0 = copysignf(2.0f, v0);
    if (fabsf(v1) > 1.0f) v1 = copysignf(2.0f, v1);

    out[b] = make_float2(v0, v1);
}

extern "C" void kernel_launch(void* const* d_in, const int* in_sizes, int n_in,
                              void* d_out, int out_size, void* d_ws, size_t ws_size,
                              hipStream_t stream) {
    const float* x  = (const float*)d_in[0];
    const float* W1 = (const float*)d_in[1];
    const float* b1 = (const float*)d_in[2];
    const float* W2 = (const float*)d_in[3];
    const float* b2 = (const float*)d_in[4];
    const float* W3 = (const float*)d_in[5];
    const float* b3 = (const float*)d_in[6];
    const int*   idx = (const int*)d_in[7];
    float2* out = (float2*)d_out;

    int nitems = in_sizes[0] / ITEM_F;   // 1048576
    int grid = (nitems + BLOCK - 1) / BLOCK;
    maddpg_kernel<<<grid, BLOCK, 0, stream>>>(x, W1, b1, W2, b2, W3, b3, idx,
                                              out, nitems);
}

// Round 2
// 933.385 us; speedup vs baseline: 1.0890x; 1.0890x over previous
//
#include <hip/hip_runtime.h>
#include <math.h>

// MADDPG actor inference: obs-build + 39->64->64->5 MLP, B=1M items.
// One thread per item. Fully unrolled => all activations in registers
// (constant indices), no LDS. Weights are wave-uniform -> scalar loads.
// float2 ext-vector + elementwise_fma to elicit v_pk_fma_f32 (2 FMA/instr).
// Obstacle rows skipped wave-uniformly when no lane is inside RADIUS
// (p~70% per obstacle): mask true with p~0.6%/lane.

#define NROW 20
#define NF   7
#define ITEM_F (NROW * NF)   // 140 floats per item
#define BLOCK 256

typedef float v2 __attribute__((ext_vector_type(2)));

__device__ __forceinline__ void row_fma(v2 (&h)[32], float o,
                                        const float* __restrict__ wrow) {
    const v2* w = (const v2*)wrow;   // rows are 256B-aligned (64 floats)
    #pragma unroll
    for (int k = 0; k < 32; k++) {
        v2 ov; ov.x = o; ov.y = o;
        h[k] = __builtin_elementwise_fma(ov, w[k], h[k]);
    }
}

__global__ __launch_bounds__(BLOCK, 2) void maddpg_kernel(
    const float* __restrict__ x,
    const float* __restrict__ W1, const float* __restrict__ b1,
    const float* __restrict__ W2, const float* __restrict__ b2,
    const float* __restrict__ W3, const float* __restrict__ b3,
    const int*   __restrict__ idx,
    float2*      __restrict__ out,
    int nitems)
{
    const int tid = threadIdx.x;
    const long b  = (long)blockIdx.x * BLOCK + tid;
    if (b >= nitems) return;

    const float* xb = x + b * (long)ITEM_F;

    // ---------------- gather x ----------------
    float4 s0 = *(const float4*)(xb);   // x[b,0,0..3]
    float  s4 = xb[4];
    const float px = s0.x, py = s0.y;

    float mo[6];                        // mid: 2 nonzero entries per t
    #pragma unroll
    for (int t = 0; t < 3; t++) {
        const float* xr = xb + idx[t] * NF;
        float2 p01 = *(const float2*)(xr);
        float2 p56 = *(const float2*)(xr + 5);
        mo[2*t + 0] = p56.x + p01.x - px;
        mo[2*t + 1] = p56.y + p01.y - py;
    }

    float oa[5][5];
    int   anyt[5];
    #pragma unroll
    for (int t = 0; t < 5; t++) {
        const float* xr = xb + (idx[3 + t] + NROW/2) * NF;
        float4 q  = *(const float4*)(xr);
        float  q4 = xr[4];
        float dx = q.x - px, dy = q.y - py;
        bool  m  = sqrtf(dx*dx + dy*dy) < 0.15f;
        oa[t][0] = m ? dx  : 0.0f;
        oa[t][1] = m ? dy  : 0.0f;
        oa[t][2] = m ? q.z : 0.0f;
        oa[t][3] = m ? q.w : 0.0f;
        oa[t][4] = m ? q4  : 0.0f;
        anyt[t]  = __any(m);            // wave-uniform skip flag
    }

    // ---------------- layer 1: 39 -> 64 (rows 7,10,13 are zero) -------------
    v2 h[32];
    const v2* b1v = (const v2*)b1;
    #pragma unroll
    for (int k = 0; k < 32; k++) h[k] = b1v[k];

    row_fma(h, s0.x, W1 + 0*64);
    row_fma(h, s0.y, W1 + 1*64);
    row_fma(h, s0.z, W1 + 2*64);
    row_fma(h, s0.w, W1 + 3*64);
    row_fma(h, s4,   W1 + 4*64);
    #pragma unroll
    for (int t = 0; t < 3; t++) {
        row_fma(h, mo[2*t + 0], W1 + (5 + 3*t)*64);
        row_fma(h, mo[2*t + 1], W1 + (6 + 3*t)*64);
    }
    #pragma unroll
    for (int t = 0; t < 5; t++) {
        if (anyt[t]) {                  // uniform branch: skip all-zero block
            #pragma unroll
            for (int j = 0; j < 5; j++)
                row_fma(h, oa[t][j], W1 + (14 + 5*t + j)*64);
        }
    }

    // relu
    v2 a[32];
    #pragma unroll
    for (int k = 0; k < 32; k++) {
        a[k].x = fmaxf(h[k].x, 0.0f);
        a[k].y = fmaxf(h[k].y, 0.0f);
    }

    // ---------------- layer 2: 64 -> 64 ----------------
    const v2* b2v = (const v2*)b2;
    #pragma unroll
    for (int k = 0; k < 32; k++) h[k] = b2v[k];
    #pragma unroll
    for (int i = 0; i < 64; i++) {
        float o = (i & 1) ? a[i >> 1].y : a[i >> 1].x;
        row_fma(h, o, W2 + i*64);
    }
    #pragma unroll
    for (int k = 0; k < 32; k++) {
        a[k].x = fmaxf(h[k].x, 0.0f);
        a[k].y = fmaxf(h[k].y, 0.0f);
    }

    // ---------------- layer 3: only cols 1..4 needed ----------------
    v2 rA; rA.x = b3[1]; rA.y = b3[2];
    v2 rB; rB.x = b3[3]; rB.y = b3[4];
    #pragma unroll
    for (int i = 0; i < 64; i++) {
        float o = (i & 1) ? a[i >> 1].y : a[i >> 1].x;
        const float* w = W3 + i*5;
        v2 ov; ov.x = o; ov.y = o;
        v2 wA; wA.x = w[1]; wA.y = w[2];
        v2 wB; wB.x = w[3]; wB.y = w[4];
        rA = __builtin_elementwise_fma(ov, wA, rA);
        rB = __builtin_elementwise_fma(ov, wB, rB);
    }

    float v0 = (rA.x - rA.y) * 0.1f;
    float v1 = (rB.x - rB.y) * 0.1f;
    if (fabsf(v0) > 1.0f) v0 = copysignf(2.0f, v0);
    if (fabsf(v1) > 1.0f) v1 = copysignf(2.0f, v1);

    out[b] = make_float2(v0, v1);
}

extern "C" void kernel_launch(void* const* d_in, const int* in_sizes, int n_in,
                              void* d_out, int out_size, void* d_ws, size_t ws_size,
                              hipStream_t stream) {
    const float* x  = (const float*)d_in[0];
    const float* W1 = (const float*)d_in[1];
    const float* b1 = (const float*)d_in[2];
    const float* W2 = (const float*)d_in[3];
    const float* b2 = (const float*)d_in[4];
    const float* W3 = (const float*)d_in[5];
    const float* b3 = (const float*)d_in[6];
    const int*   idx = (const int*)d_in[7];
    float2* out = (float2*)d_out;

    int nitems = in_sizes[0] / ITEM_F;   // 1048576
    int grid = (nitems + BLOCK - 1) / BLOCK;
    maddpg_kernel<<<grid, BLOCK, 0, stream>>>(x, W1, b1, W2, b2, W3, b3, idx,
                                              out, nitems);
}